// Round 4
// baseline (235.220 us; speedup 1.0000x reference)
//
#include <hip/hip_runtime.h>
#include <stdint.h>
#include <math.h>

namespace {

constexpr int kB  = 2;
constexpr int kS  = 2048;
constexpr int kD  = 1024;
constexpr int kH  = 16;
constexpr int kHD = 64;
constexpr int kBS = kB * kS;   // 4096
constexpr int kD3 = 3 * kD;    // 3072

typedef __attribute__((ext_vector_type(8)))  __bf16 bf16x8;
typedef __attribute__((ext_vector_type(4)))  float  f32x4;
typedef __attribute__((ext_vector_type(16))) float  f32x16;

__device__ __forceinline__ unsigned short f2bf(float f) {
  unsigned u = __float_as_uint(f);
  u += 0x7fffu + ((u >> 16) & 1u);          // RNE
  return (unsigned short)(u >> 16);
}
__device__ __forceinline__ float bf2f(unsigned short b) {
  return __uint_as_float(((unsigned)b) << 16);
}
__device__ __forceinline__ unsigned pk2(float lo, float hi) {
  return (unsigned)f2bf(lo) | ((unsigned)f2bf(hi) << 16);
}
__device__ __forceinline__ unsigned cvtpk(float lo, float hi) {
  unsigned r;
  asm("v_cvt_pk_bf16_f32 %0, %1, %2" : "=v"(r) : "v"(lo), "v"(hi));
  return r;
}
__device__ __forceinline__ float max3f(float a, float b, float c) {
  float d;
  asm("v_max3_f32 %0, %1, %2, %3" : "=v"(d) : "v"(a), "v"(b), "v"(c));
  return d;
}
__device__ __forceinline__ void gload_lds16(const void* g, void* l) {
  __builtin_amdgcn_global_load_lds((const __attribute__((address_space(1))) void*)g,
                                   (__attribute__((address_space(3))) void*)l, 16, 0, 0);
}

// ---------------- f32 -> bf16 (4 elems/thread) ----------------
__global__ __launch_bounds__(256) void cvt_kernel(const float* __restrict__ in,
                                                  unsigned short* __restrict__ out) {
  int i = blockIdx.x * 256 + threadIdx.x;
  float4 v = reinterpret_cast<const float4*>(in)[i];
  uint2 o;
  o.x = pk2(v.x, v.y);
  o.y = pk2(v.z, v.w);
  reinterpret_cast<uint2*>(out)[i] = o;
}

// ---------------- mask dtype detection ----------------
__global__ void detect_kernel(const unsigned* __restrict__ attn, unsigned* __restrict__ flag) {
  __shared__ int bad[4];
  unsigned v = attn[threadIdx.x];
  bool isbad = (v != 0u) && (v != 1u) && (v != 0x3f800000u);
  unsigned long long bal = __ballot(isbad);
  if ((threadIdx.x & 63) == 0) bad[threadIdx.x >> 6] = (bal != 0ull) ? 1 : 0;
  __syncthreads();
  if (threadIdx.x == 0) *flag = (bad[0] | bad[1] | bad[2] | bad[3]) ? 1u : 0u;
}

// ---------------- packed merged mask: bit k of word [b][q][kt] ----------------
__global__ __launch_bounds__(256) void maskpack_kernel(const int* __restrict__ attn,
                                                       const int* __restrict__ kv,
                                                       const unsigned* __restrict__ flag,
                                                       unsigned* __restrict__ out) {
  int idx = blockIdx.x * 256 + threadIdx.x;    // (b*kS + q)*64 + w
  int w = idx & 63;
  int q = (idx >> 6) & (kS - 1);
  int b = idx >> 17;
  unsigned m = 0;
  if (*flag == 0u) {
    const int* ap = attn + ((size_t)(b * kS + q)) * kS + w * 32;
    const int* kp = kv + b * kS + w * 32;
#pragma unroll
    for (int i = 0; i < 32; i++)
      if ((ap[i] != 0) & (kp[i] != 0)) m |= (1u << i);
  } else {
    const unsigned char* ap = (const unsigned char*)attn + ((size_t)(b * kS + q)) * kS + w * 32;
    const unsigned char* kp = (const unsigned char*)kv + b * kS + w * 32;
#pragma unroll
    for (int i = 0; i < 32; i++)
      if ((ap[i] != 0) & (kp[i] != 0)) m |= (1u << i);
  }
  out[idx] = m;
}

// ---------------- GEMM: C[M,N] = A[M,K] @ Bt[N,K]^T (+bias), bf16 in, f32 acc ----------------
template <int OUT_BF16, int HAS_BIAS>
__global__ __launch_bounds__(256) void gemm_kernel(const unsigned short* __restrict__ A,
                                                   const unsigned short* __restrict__ Bt,
                                                   void* __restrict__ Cv,
                                                   const float* __restrict__ bias,
                                                   int M, int N, int K) {
  __shared__ alignas(16) unsigned short As[128 * 32];
  __shared__ alignas(16) unsigned short Bs[128 * 32];
  const int tid  = threadIdx.x;
  const int lane = tid & 63;
  const int wave = tid >> 6;
  const int wr = wave >> 1, wc = wave & 1;
  const int bm = blockIdx.x * 128;
  const int bn = blockIdx.y * 128;

  f32x4 acc[4][4] = {};

  const int srow  = tid >> 2;
  const int sslot = (tid & 3) ^ ((tid >> 3) & 3);
  const unsigned short* ga = A + (size_t)(bm + srow) * K + sslot * 8;
  const unsigned short* gb = Bt + (size_t)(bn + srow) * K + sslot * 8;
  unsigned short* lA = As + wave * 512;
  unsigned short* lB = Bs + wave * 512;

  for (int kk = 0; kk < K; kk += 32) {
    __syncthreads();
    gload_lds16(ga, lA);
    gload_lds16(ga + (size_t)64 * K, lA + 64 * 32);
    gload_lds16(gb, lB);
    gload_lds16(gb + (size_t)64 * K, lB + 64 * 32);
    ga += 32; gb += 32;
    __syncthreads();

    bf16x8 af[4], bfr[4];
#pragma unroll
    for (int i = 0; i < 4; i++) {
      int rA = wr * 64 + i * 16 + (lane & 15);
      int sA = (lane >> 4) ^ ((rA >> 1) & 3);
      af[i] = *(const bf16x8*)(As + rA * 32 + sA * 8);
      int rB = wc * 64 + i * 16 + (lane & 15);
      int sB = (lane >> 4) ^ ((rB >> 1) & 3);
      bfr[i] = *(const bf16x8*)(Bs + rB * 32 + sB * 8);
    }
#pragma unroll
    for (int mi = 0; mi < 4; mi++)
#pragma unroll
      for (int ni = 0; ni < 4; ni++)
        acc[mi][ni] = __builtin_amdgcn_mfma_f32_16x16x32_bf16(af[mi], bfr[ni], acc[mi][ni], 0, 0, 0);
  }

  const int r0 = bm + wr * 64 + (lane >> 4) * 4;
  const int c0 = bn + wc * 64 + (lane & 15);
#pragma unroll
  for (int ni = 0; ni < 4; ni++) {
    int c = c0 + ni * 16;
    float bv = HAS_BIAS ? bias[c] : 0.0f;
#pragma unroll
    for (int mi = 0; mi < 4; mi++) {
#pragma unroll
      for (int j = 0; j < 4; j++) {
        int r = r0 + mi * 16 + j;
        float v = acc[mi][ni][j] + bv;
        if (OUT_BF16) ((unsigned short*)Cv)[(size_t)r * N + c] = f2bf(v);
        else          ((float*)Cv)[(size_t)r * N + c] = v;
      }
    }
  }
}

// ---------------- flash attention, KVBLK=64, double-buffered, 1 barrier/tile ----------------
// SPLIT: blockIdx.z partitions the key range (flash-decode). SPLIT==1 writes bf16
// output directly; SPLIT>1 writes unnormalized f32 partials + (m,l) for combine.
template <int SPLIT>
__global__ __launch_bounds__(512, 4) void attn_kernel(const unsigned short* __restrict__ qkv,
                                                      const unsigned* __restrict__ maskp,
                                                      unsigned short* __restrict__ aout,
                                                      float* __restrict__ po,
                                                      float2* __restrict__ pml) {
  constexpr int NT = 32 / SPLIT;            // 64-key tiles per block
  __shared__ alignas(16) unsigned short Ks[2][64 * 64];   // [key][hd], 16B slot ^= key&7
  __shared__ alignas(16) unsigned short Vt[2][64 * 64];   // [hd][key], 16B slot ^= hd&7
  const int tid  = threadIdx.x;
  const int lane = tid & 63;
  const int wave = tid >> 6;
  const int half = lane >> 5;
  const int l31  = lane & 31;
  const int b = blockIdx.y >> 4;
  const int h = blockIdx.y & 15;
  const int qrow = blockIdx.x * 256 + wave * 32 + l31;
  const int t0 = blockIdx.z * NT;           // first tile of this split
  const float NEGINF = -__builtin_inff();
  const float K2 = 1.4426950408889634f;     // log2(e)

  // Q fragments (B-operand), pre-scaled by 1/sqrt(HD)=0.125 (exact in bf16)
  bf16x8 qf[4];
  {
    const unsigned short* qp = qkv + (size_t)(b * kS + qrow) * kD3 + h * kHD + half * 8;
#pragma unroll
    for (int i = 0; i < 4; i++) {
      uint4 u = *(const uint4*)(qp + i * 16);
      unsigned w[4] = {u.x, u.y, u.z, u.w};
      union { unsigned u[4]; bf16x8 v; } o;
#pragma unroll
      for (int j = 0; j < 4; j++) {
        float lo = bf2f((unsigned short)(w[j] & 0xffffu)) * 0.125f;
        float hi = bf2f((unsigned short)(w[j] >> 16)) * 0.125f;
        o.u[j] = pk2(lo, hi);
      }
      qf[i] = o.v;
    }
  }

  f32x16 ot0 = {}, ot1 = {};                 // O^T acc: hd 0-31 / 32-63, col=qrow
  float mrun = NEGINF, lrun = 0.f, m2 = 0.f; // m2 = mrun*log2e
  const unsigned* mp = maskp + ((size_t)(b * kS) + qrow) * 64 + 2 * t0;

  // K staging: thread t covers 16B chunk: row=t>>3, dest slot=t&7; source pre-swizzled
  const int krow  = tid >> 3;
  const int kslot = (tid & 7) ^ (krow & 7);
  const unsigned short* gk = qkv + (size_t)(b * kS + t0 * 64 + krow) * kD3 + kD + h * kHD + kslot * 8;

  // V staging (register transpose, b64 writes): thread -> (vp: hd pair, vo: key octet, vh: half-octet)
  const int vp = tid >> 4;          // 0..31 -> hd {2vp, 2vp+1}
  const int vo = (tid >> 1) & 7;    // key octet: keys 8vo..8vo+7
  const int vh = tid & 1;           // which 4 keys of the octet
  const unsigned short* gv = qkv + (size_t)(b * kS + t0 * 64 + 8 * vo + 4 * vh) * kD3 + 2 * kD + h * kHD + 2 * vp;
  const int vwo_lo = (2 * vp) * 128 + ((vo ^ ((2 * vp) & 7)) << 4) + vh * 8;           // bytes
  const int vwo_hi = (2 * vp + 1) * 128 + ((vo ^ ((2 * vp + 1) & 7)) << 4) + vh * 8;

  // prologue: stage tile 0 into buf 0
  unsigned v0 = *(const unsigned*)(gv);
  unsigned v1 = *(const unsigned*)(gv + kD3);
  unsigned v2 = *(const unsigned*)(gv + 2 * kD3);
  unsigned v3 = *(const unsigned*)(gv + 3 * kD3);
  gload_lds16(gk, (unsigned short*)Ks[0] + tid * 8);
  {
    char* vb = (char*)Vt[0];
    uint2 wlo, whi;
    wlo.x = __builtin_amdgcn_perm(v1, v0, 0x05040100u);
    wlo.y = __builtin_amdgcn_perm(v3, v2, 0x05040100u);
    whi.x = __builtin_amdgcn_perm(v1, v0, 0x07060302u);
    whi.y = __builtin_amdgcn_perm(v3, v2, 0x07060302u);
    *(uint2*)(vb + vwo_lo) = wlo;
    *(uint2*)(vb + vwo_hi) = whi;
  }
  __syncthreads();

  for (int t = 0; t < NT; ++t) {
    const int cur = t & 1;
    // ---- issue next-tile staging loads (land during this tile's compute) ----
    if (t < NT - 1) {
      const unsigned short* gvn = gv + (size_t)(t + 1) * 64 * kD3;
      v0 = *(const unsigned*)(gvn);
      v1 = *(const unsigned*)(gvn + kD3);
      v2 = *(const unsigned*)(gvn + 2 * kD3);
      v3 = *(const unsigned*)(gvn + 3 * kD3);
      gload_lds16(gk + (size_t)(t + 1) * 64 * kD3, (unsigned short*)Ks[cur ^ 1] + tid * 8);
    }
    uint2 mwv = *(const uint2*)(mp + 2 * t);
    const unsigned mx = mwv.x >> (4 * half);
    const unsigned my = mwv.y >> (4 * half);

    // ---- QK^T: s0 = keys 0-31, s1 = keys 32-63 ----
    f32x16 s0 = {}, s1 = {};
    const unsigned short* ksb = Ks[cur];
    __builtin_amdgcn_s_setprio(1);
#pragma unroll
    for (int i = 0; i < 4; i++) {
      int slot = (i * 2 + half) ^ (l31 & 7);
      bf16x8 ka0 = *(const bf16x8*)(ksb + l31 * 64 + slot * 8);
      bf16x8 ka1 = *(const bf16x8*)(ksb + (l31 + 32) * 64 + slot * 8);
      s0 = __builtin_amdgcn_mfma_f32_32x32x16_bf16(ka0, qf[i], s0, 0, 0, 0);
      s1 = __builtin_amdgcn_mfma_f32_32x32x16_bf16(ka1, qf[i], s1, 0, 0, 0);
    }
    __builtin_amdgcn_s_setprio(0);

    // ---- raw tile max (masking deferred to post-exp; larger m is always safe) ----
    float pm = NEGINF;
#pragma unroll
    for (int r = 0; r < 16; r++) pm = max3f(s0[r], s1[r], pm);
    pm = fmaxf(pm, __shfl_xor(pm, 32));

    // ---- deferred rescale (T13, THR=8) ----
    if (__any(pm > mrun + 8.0f)) {
      float mn = fmaxf(mrun, pm);
      float m2n = mn * K2;
      float sc = exp2f(fmaf(mrun, K2, -m2n));   // mrun=-inf on first tile -> 0
      m2 = m2n;
      mrun = mn;
      lrun *= sc;
#pragma unroll
      for (int r = 0; r < 16; r++) { ot0[r] *= sc; ot1[r] *= sc; }
    }

    // ---- exp + mask-zero (sbfe bit -> 0/-1 mask, AND) + row-sum ----
    float ls = 0.f;
#pragma unroll
    for (int r = 0; r < 16; r++) {
      const int kb = (r & 3) + 8 * (r >> 2);   // compile-time per unrolled r
      float p0 = exp2f(fmaf(s0[r], K2, -m2));
      float p1 = exp2f(fmaf(s1[r], K2, -m2));
      unsigned z0 = (unsigned)__builtin_amdgcn_sbfe(mx, kb, 1);
      unsigned z1 = (unsigned)__builtin_amdgcn_sbfe(my, kb, 1);
      p0 = __uint_as_float(__float_as_uint(p0) & z0);
      p1 = __uint_as_float(__float_as_uint(p1) & z1);
      s0[r] = p0; s1[r] = p1;
      ls += p0 + p1;
    }
    ls += __shfl_xor(ls, 32);
    lrun += ls;

    // ---- PV: cvt_pk pack + permlane32_swap fragment assembly + MFMA vs V^T ----
    // v_permlane32_swap_b32 vdst, vsrc: swaps vdst's UPPER 32 lanes with vsrc's
    // LOWER 32 lanes => after swap(x,y): x = {x_lo, y_lo}, y = {x_hi, y_hi}.
    // Desired pb.u[0] = {w8[4cc]_lo, w8[4cc+2]_lo}, pb.u[2] = {w8[4cc]_hi, w8[4cc+2]_hi}
    // => swap(vdst=w8[4cc], vsrc=w8[4cc+2]); pb.u[0]=vdst, pb.u[2]=vsrc.  (R3 had it transposed.)
    const char* vtb = (const char*)Vt[cur];
#pragma unroll
    for (int g = 0; g < 2; g++) {
      unsigned w8[8];
#pragma unroll
      for (int j = 0; j < 8; j++)
        w8[j] = g ? cvtpk(s1[2 * j], s1[2 * j + 1]) : cvtpk(s0[2 * j], s0[2 * j + 1]);
#pragma unroll
      for (int cc = 0; cc < 2; cc++) {
        unsigned u0 = w8[4 * cc],     u2 = w8[4 * cc + 2];
        unsigned u1 = w8[4 * cc + 1], u3 = w8[4 * cc + 3];
        asm("v_permlane32_swap_b32 %0, %1" : "+v"(u0), "+v"(u2));
        asm("v_permlane32_swap_b32 %0, %1" : "+v"(u1), "+v"(u3));
        union { unsigned u[4]; bf16x8 v; } pb;
        pb.u[0] = u0; pb.u[1] = u1; pb.u[2] = u2; pb.u[3] = u3;
        int c = g * 2 + cc;
        int kslotc = (c * 2 + half) ^ (l31 & 7);
        __builtin_amdgcn_s_setprio(1);
        {
          bf16x8 va0 = *(const bf16x8*)(vtb + l31 * 128 + kslotc * 16);
          bf16x8 va1 = *(const bf16x8*)(vtb + (l31 + 32) * 128 + kslotc * 16);
          ot0 = __builtin_amdgcn_mfma_f32_32x32x16_bf16(va0, pb.v, ot0, 0, 0, 0);
          ot1 = __builtin_amdgcn_mfma_f32_32x32x16_bf16(va1, pb.v, ot1, 0, 0, 0);
        }
        __builtin_amdgcn_s_setprio(0);
      }
    }

    // ---- write next V tile into LDS (vregs arrived during compute) ----
    if (t < NT - 1) {
      char* vb = (char*)Vt[cur ^ 1];
      uint2 wlo, whi;
      wlo.x = __builtin_amdgcn_perm(v1, v0, 0x05040100u);
      wlo.y = __builtin_amdgcn_perm(v3, v2, 0x05040100u);
      whi.x = __builtin_amdgcn_perm(v1, v0, 0x07060302u);
      whi.y = __builtin_amdgcn_perm(v3, v2, 0x07060302u);
      *(uint2*)(vb + vwo_lo) = wlo;
      *(uint2*)(vb + vwo_hi) = whi;
    }
    __syncthreads();
  }

  if (SPLIT == 1) {
    // ---- normalize + write a_out bf16 (fully-masked row -> 0) ----
    float rl = (lrun > 0.f) ? (1.f / lrun) : 0.f;
    unsigned short* op = aout + (size_t)(b * kS + qrow) * kD + h * kHD;
#pragma unroll
    for (int hh = 0; hh < 2; hh++) {
#pragma unroll
      for (int qd = 0; qd < 4; qd++) {
        float x0 = (hh ? ot1[4 * qd]     : ot0[4 * qd])     * rl;
        float x1 = (hh ? ot1[4 * qd + 1] : ot0[4 * qd + 1]) * rl;
        float x2 = (hh ? ot1[4 * qd + 2] : ot0[4 * qd + 2]) * rl;
        float x3 = (hh ? ot1[4 * qd + 3] : ot0[4 * qd + 3]) * rl;
        uint2 o;
        o.x = pk2(x0, x1);
        o.y = pk2(x2, x3);
        *(uint2*)(op + hh * 32 + qd * 8 + half * 4) = o;
      }
    }
  } else {
    // ---- write unnormalized f32 partial + (m, l) ----
    const int prow = blockIdx.y * kS + qrow;
    float* pb = po + (size_t)blockIdx.z * (32 * kS * 64) + (size_t)prow * 64;
#pragma unroll
    for (int qd = 0; qd < 4; qd++) {
      f32x4 q0 = {ot0[4 * qd], ot0[4 * qd + 1], ot0[4 * qd + 2], ot0[4 * qd + 3]};
      f32x4 q1 = {ot1[4 * qd], ot1[4 * qd + 1], ot1[4 * qd + 2], ot1[4 * qd + 3]};
      *(f32x4*)(pb + 8 * qd + 4 * half)      = q0;   // hd = 8qd + 4half + j
      *(f32x4*)(pb + 32 + 8 * qd + 4 * half) = q1;   // hd = 32 + ...
    }
    if (half == 0) {
      float2 v; v.x = mrun; v.y = lrun;
      pml[(size_t)blockIdx.z * (32 * kS) + prow] = v;
    }
  }
}

// ---------------- combine 2 KV-split partials ----------------
__global__ __launch_bounds__(256) void combine_kernel(const float* __restrict__ po,
                                                      const float2* __restrict__ pml,
                                                      unsigned short* __restrict__ aout) {
  const float K2 = 1.4426950408889634f;
  int idx = blockIdx.x * 256 + threadIdx.x;   // 32*2048*16
  int hq  = idx & 15;
  int row = idx >> 4;                          // bh*2048 + q
  float2 ml0 = pml[row];
  float2 ml1 = pml[row + 32 * kS];
  float M  = fmaxf(ml0.x, ml1.x);
  float w0 = exp2f((ml0.x - M) * K2);
  float w1 = exp2f((ml1.x - M) * K2);
  float den = ml0.y * w0 + ml1.y * w1;
  float rd = (den > 0.f) ? (1.f / den) : 0.f;
  w0 *= rd; w1 *= rd;
  float4 o0 = ((const float4*)po)[(size_t)row * 16 + hq];
  float4 o1 = ((const float4*)(po + (size_t)32 * kS * 64))[(size_t)row * 16 + hq];
  int bh = row >> 11, q = row & (kS - 1);
  int b = bh >> 4, h = bh & 15;
  unsigned short* op = aout + ((size_t)(b * kS + q)) * kD + h * kHD + hq * 4;
  uint2 o;
  o.x = pk2(o0.x * w0 + o1.x * w1, o0.y * w0 + o1.y * w1);
  o.y = pk2(o0.z * w0 + o1.z * w1, o0.w * w0 + o1.w * w1);
  *(uint2*)op = o;
}

}  // namespace

extern "C" void kernel_launch(void* const* d_in, const int* in_sizes, int n_in,
                              void* d_out, int out_size, void* d_ws, size_t ws_size,
                              hipStream_t stream) {
  (void)in_sizes; (void)n_in; (void)out_size;
  const float* q     = (const float*)d_in[0];
  const int*   kvm   = (const int*)d_in[1];
  const int*   am    = (const int*)d_in[2];
  const float* W_all = (const float*)d_in[3];
  const float* W_out = (const float*)d_in[4];
  const float* b_out = (const float*)d_in[5];

  char* ws = (char*)d_ws;
  unsigned short* qkv  = (unsigned short*)(ws);                    // 25,165,824 B
  unsigned short* qbf  = (unsigned short*)(ws + 25165824);         //  8,388,608 B (reused as aout)
  unsigned short* aout = qbf;
  unsigned short* wabf = (unsigned short*)(ws + 33554432);         //  6,291,456 B
  unsigned short* wobf = (unsigned short*)(ws + 39845888);         //  2,097,152 B
  unsigned*       mskp = (unsigned*)(ws + 41943040);               //  1,048,576 B
  unsigned*       flag = (unsigned*)(ws + 42991616);               //          4 B
  float2*         pml  = (float2*)(ws + 42995712);                 //  1,048,576 B (2 x 65536 x 8)
  float*          po   = (float*)(ws + 44044288);                  // 33,554,432 B (2 x 65536 x 64 x 4)
  const bool split = ws_size >= 77598720ull;

  detect_kernel<<<1, 256, 0, stream>>>((const unsigned*)am, flag);
  maskpack_kernel<<<1024, 256, 0, stream>>>(am, kvm, flag, mskp);
  cvt_kernel<<<4096, 256, 0, stream>>>(q, qbf);
  cvt_kernel<<<3072, 256, 0, stream>>>(W_all, wabf);
  cvt_kernel<<<1024, 256, 0, stream>>>(W_out, wobf);
  // qkv[4096,3072] = q_bf @ W_all^T
  gemm_kernel<1, 0><<<dim3(kBS / 128, kD3 / 128), 256, 0, stream>>>(qbf, wabf, qkv, nullptr, kBS, kD3, kD);
  // a_out[4096,1024] (bf16)
  if (split) {
    attn_kernel<2><<<dim3(kS / 256, kB * kH, 2), 512, 0, stream>>>(qkv, mskp, aout, po, pml);
    combine_kernel<<<(32 * kS * 16) / 256, 256, 0, stream>>>(po, pml, aout);
  } else {
    attn_kernel<1><<<dim3(kS / 256, kB * kH, 1), 512, 0, stream>>>(qkv, mskp, aout, po, pml);
  }
  // out[4096,1024] = a_out @ W_out^T + b_out (f32)
  gemm_kernel<0, 1><<<dim3(kBS / 128, kD / 128), 256, 0, stream>>>(aout, wobf, d_out, b_out, kBS, kD, kD);
}

// Round 5
// 184.274 us; speedup vs baseline: 1.2765x; 1.2765x over previous
//
#include <hip/hip_runtime.h>
#include <stdint.h>
#include <math.h>

namespace {

constexpr int kB  = 2;
constexpr int kS  = 2048;
constexpr int kD  = 1024;
constexpr int kH  = 16;
constexpr int kHD = 64;
constexpr int kBS = kB * kS;   // 4096
constexpr int kD3 = 3 * kD;    // 3072

typedef __attribute__((ext_vector_type(8)))  __bf16 bf16x8;
typedef __attribute__((ext_vector_type(4)))  float  f32x4;
typedef __attribute__((ext_vector_type(16))) float  f32x16;

__device__ __forceinline__ unsigned short f2bf(float f) {
  unsigned u = __float_as_uint(f);
  u += 0x7fffu + ((u >> 16) & 1u);          // RNE
  return (unsigned short)(u >> 16);
}
__device__ __forceinline__ float bf2f(unsigned short b) {
  return __uint_as_float(((unsigned)b) << 16);
}
__device__ __forceinline__ unsigned pk2(float lo, float hi) {
  return (unsigned)f2bf(lo) | ((unsigned)f2bf(hi) << 16);
}
__device__ __forceinline__ unsigned cvtpk(float lo, float hi) {
  unsigned r;
  asm("v_cvt_pk_bf16_f32 %0, %1, %2" : "=v"(r) : "v"(lo), "v"(hi));
  return r;
}
__device__ __forceinline__ float max3f(float a, float b, float c) {
  float d;
  asm("v_max3_f32 %0, %1, %2, %3" : "=v"(d) : "v"(a), "v"(b), "v"(c));
  return d;
}
__device__ __forceinline__ void gload_lds16(const void* g, void* l) {
  __builtin_amdgcn_global_load_lds((const __attribute__((address_space(1))) void*)g,
                                   (__attribute__((address_space(3))) void*)l, 16, 0, 0);
}

// ---------------- f32 -> bf16 (4 elems/thread) ----------------
__global__ __launch_bounds__(256) void cvt_kernel(const float* __restrict__ in,
                                                  unsigned short* __restrict__ out) {
  int i = blockIdx.x * 256 + threadIdx.x;
  float4 v = reinterpret_cast<const float4*>(in)[i];
  uint2 o;
  o.x = pk2(v.x, v.y);
  o.y = pk2(v.z, v.w);
  reinterpret_cast<uint2*>(out)[i] = o;
}

// ---------------- mask dtype detection ----------------
__global__ void detect_kernel(const unsigned* __restrict__ attn, unsigned* __restrict__ flag) {
  __shared__ int bad[4];
  unsigned v = attn[threadIdx.x];
  bool isbad = (v != 0u) && (v != 1u) && (v != 0x3f800000u);
  unsigned long long bal = __ballot(isbad);
  if ((threadIdx.x & 63) == 0) bad[threadIdx.x >> 6] = (bal != 0ull) ? 1 : 0;
  __syncthreads();
  if (threadIdx.x == 0) *flag = (bad[0] | bad[1] | bad[2] | bad[3]) ? 1u : 0u;
}

// ---------------- packed merged mask: bit k of word [b][q][kt] ----------------
__global__ __launch_bounds__(256) void maskpack_kernel(const int* __restrict__ attn,
                                                       const int* __restrict__ kv,
                                                       const unsigned* __restrict__ flag,
                                                       unsigned* __restrict__ out) {
  int idx = blockIdx.x * 256 + threadIdx.x;    // (b*kS + q)*64 + w
  int w = idx & 63;
  int q = (idx >> 6) & (kS - 1);
  int b = idx >> 17;
  unsigned m = 0;
  if (*flag == 0u) {
    const int* ap = attn + ((size_t)(b * kS + q)) * kS + w * 32;
    const int* kp = kv + b * kS + w * 32;
#pragma unroll
    for (int i = 0; i < 32; i++)
      if ((ap[i] != 0) & (kp[i] != 0)) m |= (1u << i);
  } else {
    const unsigned char* ap = (const unsigned char*)attn + ((size_t)(b * kS + q)) * kS + w * 32;
    const unsigned char* kp = (const unsigned char*)kv + b * kS + w * 32;
#pragma unroll
    for (int i = 0; i < 32; i++)
      if ((ap[i] != 0) & (kp[i] != 0)) m |= (1u << i);
  }
  out[idx] = m;
}

// ---------------- GEMM: C[M,N] = A[M,K] @ Bt[N,K]^T (+bias), bf16 in, f32 acc ----------------
template <int OUT_BF16, int HAS_BIAS>
__global__ __launch_bounds__(256) void gemm_kernel(const unsigned short* __restrict__ A,
                                                   const unsigned short* __restrict__ Bt,
                                                   void* __restrict__ Cv,
                                                   const float* __restrict__ bias,
                                                   int M, int N, int K) {
  __shared__ alignas(16) unsigned short As[128 * 32];
  __shared__ alignas(16) unsigned short Bs[128 * 32];
  const int tid  = threadIdx.x;
  const int lane = tid & 63;
  const int wave = tid >> 6;
  const int wr = wave >> 1, wc = wave & 1;
  const int bm = blockIdx.x * 128;
  const int bn = blockIdx.y * 128;

  f32x4 acc[4][4] = {};

  const int srow  = tid >> 2;
  const int sslot = (tid & 3) ^ ((tid >> 3) & 3);
  const unsigned short* ga = A + (size_t)(bm + srow) * K + sslot * 8;
  const unsigned short* gb = Bt + (size_t)(bn + srow) * K + sslot * 8;
  unsigned short* lA = As + wave * 512;
  unsigned short* lB = Bs + wave * 512;

  for (int kk = 0; kk < K; kk += 32) {
    __syncthreads();
    gload_lds16(ga, lA);
    gload_lds16(ga + (size_t)64 * K, lA + 64 * 32);
    gload_lds16(gb, lB);
    gload_lds16(gb + (size_t)64 * K, lB + 64 * 32);
    ga += 32; gb += 32;
    __syncthreads();

    bf16x8 af[4], bfr[4];
#pragma unroll
    for (int i = 0; i < 4; i++) {
      int rA = wr * 64 + i * 16 + (lane & 15);
      int sA = (lane >> 4) ^ ((rA >> 1) & 3);
      af[i] = *(const bf16x8*)(As + rA * 32 + sA * 8);
      int rB = wc * 64 + i * 16 + (lane & 15);
      int sB = (lane >> 4) ^ ((rB >> 1) & 3);
      bfr[i] = *(const bf16x8*)(Bs + rB * 32 + sB * 8);
    }
#pragma unroll
    for (int mi = 0; mi < 4; mi++)
#pragma unroll
      for (int ni = 0; ni < 4; ni++)
        acc[mi][ni] = __builtin_amdgcn_mfma_f32_16x16x32_bf16(af[mi], bfr[ni], acc[mi][ni], 0, 0, 0);
  }

  const int r0 = bm + wr * 64 + (lane >> 4) * 4;
  const int c0 = bn + wc * 64 + (lane & 15);
#pragma unroll
  for (int ni = 0; ni < 4; ni++) {
    int c = c0 + ni * 16;
    float bv = HAS_BIAS ? bias[c] : 0.0f;
#pragma unroll
    for (int mi = 0; mi < 4; mi++) {
#pragma unroll
      for (int j = 0; j < 4; j++) {
        int r = r0 + mi * 16 + j;
        float v = acc[mi][ni][j] + bv;
        if (OUT_BF16) ((unsigned short*)Cv)[(size_t)r * N + c] = f2bf(v);
        else          ((float*)Cv)[(size_t)r * N + c] = v;
      }
    }
  }
}

// ---------------- flash attention, KVBLK=64, double-buffered, 1 barrier/tile ----------------
// Grid: x = bh (32), y = q-chunk (8). Same-head blocks differ only in y =>
// linear id ≡ bh (mod 8) => all 8 land on ONE XCD => K/V (512 KB/head,
// 2 MB/XCD for 4 heads) stays L2-resident instead of being re-fetched 8x.
// 512 threads = 8 waves; block covers 256 q-rows (32/wave).
// Swapped QK^T: D[key][qrow] via mfma_32x32x16(A=K, B=Q). Lane l owns q-row (l&31).
// PV computes O^T[hd][q] via A=V^T (LDS, reg-transposed stage), B=P^T.
__global__ __launch_bounds__(512) void attn_kernel(const unsigned short* __restrict__ qkv,   // [4096][3072]
                                                   const unsigned* __restrict__ maskp,       // [B][S][64]
                                                   unsigned short* __restrict__ aout) {      // [4096][1024]
  __shared__ alignas(16) unsigned short Ks[2][64 * 64];   // [key][hd], 16B slot ^= key&7
  __shared__ alignas(16) unsigned short Vt[2][64 * 64];   // [hd][key], 16B slot ^= hd&7
  const int tid  = threadIdx.x;
  const int lane = tid & 63;
  const int wave = tid >> 6;
  const int half = lane >> 5;
  const int l31  = lane & 31;
  const int b = blockIdx.x >> 4;
  const int h = blockIdx.x & 15;
  const int qrow = blockIdx.y * 256 + wave * 32 + l31;
  const float NEGINF = -__builtin_inff();
  const float K2 = 1.4426950408889634f;     // log2(e)

  // Q fragments (B-operand), pre-scaled by 1/sqrt(HD)=0.125 (exact in bf16)
  bf16x8 qf[4];
  {
    const unsigned short* qp = qkv + (size_t)(b * kS + qrow) * kD3 + h * kHD + half * 8;
#pragma unroll
    for (int i = 0; i < 4; i++) {
      uint4 u = *(const uint4*)(qp + i * 16);
      unsigned w[4] = {u.x, u.y, u.z, u.w};
      union { unsigned u[4]; bf16x8 v; } o;
#pragma unroll
      for (int j = 0; j < 4; j++) {
        float lo = bf2f((unsigned short)(w[j] & 0xffffu)) * 0.125f;
        float hi = bf2f((unsigned short)(w[j] >> 16)) * 0.125f;
        o.u[j] = pk2(lo, hi);
      }
      qf[i] = o.v;
    }
  }

  f32x16 ot0 = {}, ot1 = {};                 // O^T acc: hd 0-31 / 32-63, col=qrow
  float mrun = NEGINF, lrun = 0.f, m2 = 0.f; // m2 = mrun*log2e
  const unsigned* mp = maskp + ((size_t)(b * kS) + qrow) * 64;

  // K staging: thread t covers 16B chunk: row=t>>3, dest slot=t&7; source pre-swizzled
  const int krow  = tid >> 3;
  const int kslot = (tid & 7) ^ (krow & 7);
  const unsigned short* gk = qkv + (size_t)(b * kS + krow) * kD3 + kD + h * kHD + kslot * 8;

  // V staging (register transpose, b64 writes): thread -> (vp: hd pair, vo: key octet, vh: half-octet)
  const int vp = tid >> 4;          // 0..31 -> hd {2vp, 2vp+1}
  const int vo = (tid >> 1) & 7;    // key octet: keys 8vo..8vo+7
  const int vh = tid & 1;           // which 4 keys of the octet
  const unsigned short* gv = qkv + (size_t)(b * kS + 8 * vo + 4 * vh) * kD3 + 2 * kD + h * kHD + 2 * vp;
  const int vwo_lo = (2 * vp) * 128 + ((vo ^ ((2 * vp) & 7)) << 4) + vh * 8;           // bytes
  const int vwo_hi = (2 * vp + 1) * 128 + ((vo ^ ((2 * vp + 1) & 7)) << 4) + vh * 8;

  // prologue: stage tile 0 into buf 0
  unsigned v0 = *(const unsigned*)(gv);
  unsigned v1 = *(const unsigned*)(gv + kD3);
  unsigned v2 = *(const unsigned*)(gv + 2 * kD3);
  unsigned v3 = *(const unsigned*)(gv + 3 * kD3);
  gload_lds16(gk, (unsigned short*)Ks[0] + tid * 8);
  {
    char* vb = (char*)Vt[0];
    uint2 wlo, whi;
    wlo.x = __builtin_amdgcn_perm(v1, v0, 0x05040100u);
    wlo.y = __builtin_amdgcn_perm(v3, v2, 0x05040100u);
    whi.x = __builtin_amdgcn_perm(v1, v0, 0x07060302u);
    whi.y = __builtin_amdgcn_perm(v3, v2, 0x07060302u);
    *(uint2*)(vb + vwo_lo) = wlo;
    *(uint2*)(vb + vwo_hi) = whi;
  }
  __syncthreads();

  for (int t = 0; t < 32; ++t) {
    const int cur = t & 1;
    // ---- issue next-tile staging loads (land during this tile's compute) ----
    if (t < 31) {
      const unsigned short* gvn = gv + (size_t)(t + 1) * 64 * kD3;
      v0 = *(const unsigned*)(gvn);
      v1 = *(const unsigned*)(gvn + kD3);
      v2 = *(const unsigned*)(gvn + 2 * kD3);
      v3 = *(const unsigned*)(gvn + 3 * kD3);
      gload_lds16(gk + (size_t)(t + 1) * 64 * kD3, (unsigned short*)Ks[cur ^ 1] + tid * 8);
    }
    uint2 mwv = *(const uint2*)(mp + 2 * t);
    const unsigned mx = mwv.x >> (4 * half);
    const unsigned my = mwv.y >> (4 * half);

    // ---- QK^T: s0 = keys 0-31, s1 = keys 32-63 ----
    f32x16 s0 = {}, s1 = {};
    const unsigned short* ksb = Ks[cur];
    __builtin_amdgcn_s_setprio(1);
#pragma unroll
    for (int i = 0; i < 4; i++) {
      int slot = (i * 2 + half) ^ (l31 & 7);
      bf16x8 ka0 = *(const bf16x8*)(ksb + l31 * 64 + slot * 8);
      bf16x8 ka1 = *(const bf16x8*)(ksb + (l31 + 32) * 64 + slot * 8);
      s0 = __builtin_amdgcn_mfma_f32_32x32x16_bf16(ka0, qf[i], s0, 0, 0, 0);
      s1 = __builtin_amdgcn_mfma_f32_32x32x16_bf16(ka1, qf[i], s1, 0, 0, 0);
    }
    __builtin_amdgcn_s_setprio(0);

    // ---- raw tile max (masking deferred to post-exp; larger m is always safe) ----
    float pm = NEGINF;
#pragma unroll
    for (int r = 0; r < 16; r++) pm = max3f(s0[r], s1[r], pm);
    pm = fmaxf(pm, __shfl_xor(pm, 32));

    // ---- deferred rescale (T13, THR=8) ----
    if (__any(pm > mrun + 8.0f)) {
      float mn = fmaxf(mrun, pm);
      float m2n = mn * K2;
      float sc = __builtin_amdgcn_exp2f(fmaf(mrun, K2, -m2n));   // mrun=-inf -> 0
      m2 = m2n;
      mrun = mn;
      lrun *= sc;
#pragma unroll
      for (int r = 0; r < 16; r++) { ot0[r] *= sc; ot1[r] *= sc; }
    }

    // ---- exp + mask-zero (sbfe bit -> 0/-1 mask, AND) + row-sum ----
    float ls = 0.f;
#pragma unroll
    for (int r = 0; r < 16; r++) {
      const int kb = (r & 3) + 8 * (r >> 2);   // compile-time per unrolled r
      float p0 = __builtin_amdgcn_exp2f(fmaf(s0[r], K2, -m2));
      float p1 = __builtin_amdgcn_exp2f(fmaf(s1[r], K2, -m2));
      unsigned z0 = (unsigned)__builtin_amdgcn_sbfe(mx, kb, 1);
      unsigned z1 = (unsigned)__builtin_amdgcn_sbfe(my, kb, 1);
      p0 = __uint_as_float(__float_as_uint(p0) & z0);
      p1 = __uint_as_float(__float_as_uint(p1) & z1);
      s0[r] = p0; s1[r] = p1;
      ls += p0 + p1;
    }
    ls += __shfl_xor(ls, 32);
    lrun += ls;

    // ---- PV: cvt_pk pack + permlane32_swap fragment assembly + MFMA vs V^T ----
    // after swap(x,y): x = {x_lo, y_lo}, y = {x_hi, y_hi}
    const char* vtb = (const char*)Vt[cur];
#pragma unroll
    for (int g = 0; g < 2; g++) {
      unsigned w8[8];
#pragma unroll
      for (int j = 0; j < 8; j++)
        w8[j] = g ? cvtpk(s1[2 * j], s1[2 * j + 1]) : cvtpk(s0[2 * j], s0[2 * j + 1]);
#pragma unroll
      for (int cc = 0; cc < 2; cc++) {
        unsigned u0 = w8[4 * cc],     u2 = w8[4 * cc + 2];
        unsigned u1 = w8[4 * cc + 1], u3 = w8[4 * cc + 3];
        asm("v_permlane32_swap_b32 %0, %1" : "+v"(u0), "+v"(u2));
        asm("v_permlane32_swap_b32 %0, %1" : "+v"(u1), "+v"(u3));
        union { unsigned u[4]; bf16x8 v; } pb;
        pb.u[0] = u0; pb.u[1] = u1; pb.u[2] = u2; pb.u[3] = u3;
        int c = g * 2 + cc;
        int kslotc = (c * 2 + half) ^ (l31 & 7);
        __builtin_amdgcn_s_setprio(1);
        {
          bf16x8 va0 = *(const bf16x8*)(vtb + l31 * 128 + kslotc * 16);
          bf16x8 va1 = *(const bf16x8*)(vtb + (l31 + 32) * 128 + kslotc * 16);
          ot0 = __builtin_amdgcn_mfma_f32_32x32x16_bf16(va0, pb.v, ot0, 0, 0, 0);
          ot1 = __builtin_amdgcn_mfma_f32_32x32x16_bf16(va1, pb.v, ot1, 0, 0, 0);
        }
        __builtin_amdgcn_s_setprio(0);
      }
    }

    // ---- write next V tile into LDS (vregs arrived during compute) ----
    if (t < 31) {
      char* vb = (char*)Vt[cur ^ 1];
      uint2 wlo, whi;
      wlo.x = __builtin_amdgcn_perm(v1, v0, 0x05040100u);
      wlo.y = __builtin_amdgcn_perm(v3, v2, 0x05040100u);
      whi.x = __builtin_amdgcn_perm(v1, v0, 0x07060302u);
      whi.y = __builtin_amdgcn_perm(v3, v2, 0x07060302u);
      *(uint2*)(vb + vwo_lo) = wlo;
      *(uint2*)(vb + vwo_hi) = whi;
    }
    __syncthreads();
  }

  // ---- normalize + write a_out bf16 (fully-masked row -> 0) ----
  float rl = (lrun > 0.f) ? (1.f / lrun) : 0.f;
  unsigned short* op = aout + (size_t)(b * kS + qrow) * kD + h * kHD;
#pragma unroll
  for (int hh = 0; hh < 2; hh++) {
#pragma unroll
    for (int qd = 0; qd < 4; qd++) {
      float x0 = (hh ? ot1[4 * qd]     : ot0[4 * qd])     * rl;
      float x1 = (hh ? ot1[4 * qd + 1] : ot0[4 * qd + 1]) * rl;
      float x2 = (hh ? ot1[4 * qd + 2] : ot0[4 * qd + 2]) * rl;
      float x3 = (hh ? ot1[4 * qd + 3] : ot0[4 * qd + 3]) * rl;
      uint2 o;
      o.x = pk2(x0, x1);
      o.y = pk2(x2, x3);
      *(uint2*)(op + hh * 32 + qd * 8 + half * 4) = o;
    }
  }
}

}  // namespace

extern "C" void kernel_launch(void* const* d_in, const int* in_sizes, int n_in,
                              void* d_out, int out_size, void* d_ws, size_t ws_size,
                              hipStream_t stream) {
  (void)in_sizes; (void)n_in; (void)out_size; (void)ws_size;
  const float* q     = (const float*)d_in[0];
  const int*   kvm   = (const int*)d_in[1];
  const int*   am    = (const int*)d_in[2];
  const float* W_all = (const float*)d_in[3];
  const float* W_out = (const float*)d_in[4];
  const float* b_out = (const float*)d_in[5];

  char* ws = (char*)d_ws;
  unsigned short* qkv  = (unsigned short*)(ws);                    // 25,165,824 B
  unsigned short* qbf  = (unsigned short*)(ws + 25165824);         //  8,388,608 B (reused as aout)
  unsigned short* aout = qbf;
  unsigned short* wabf = (unsigned short*)(ws + 33554432);         //  6,291,456 B
  unsigned short* wobf = (unsigned short*)(ws + 39845888);         //  2,097,152 B
  unsigned*       mskp = (unsigned*)(ws + 41943040);               //  1,048,576 B
  unsigned*       flag = (unsigned*)(ws + 42991616);               //          4 B

  detect_kernel<<<1, 256, 0, stream>>>((const unsigned*)am, flag);
  maskpack_kernel<<<1024, 256, 0, stream>>>(am, kvm, flag, mskp);
  cvt_kernel<<<4096, 256, 0, stream>>>(q, qbf);
  cvt_kernel<<<3072, 256, 0, stream>>>(W_all, wabf);
  cvt_kernel<<<1024, 256, 0, stream>>>(W_out, wobf);
  // qkv[4096,3072] = q_bf @ W_all^T
  gemm_kernel<1, 0><<<dim3(kBS / 128, kD3 / 128), 256, 0, stream>>>(qbf, wabf, qkv, nullptr, kBS, kD3, kD);
  // a_out[4096,1024] (bf16); grid x=bh (XCD-local K/V), y=q-chunk
  attn_kernel<<<dim3(kB * kH, kS / 256), 512, 0, stream>>>(qkv, mskp, aout);
  // out[4096,1024] = a_out @ W_out^T + b_out (f32)
  gemm_kernel<0, 1><<<dim3(kBS / 128, kD / 128), 256, 0, stream>>>(aout, wobf, d_out, b_out, kBS, kD, kD);
}